// Round 5
// baseline (989.345 us; speedup 1.0000x reference)
//
#include <hip/hip_runtime.h>
#include <hip/hip_fp16.h>
#include <math.h>

// ---------------------------------------------------------------------------
// GAT 4-layer forward.  (R17 = R16 + XCD-sliced aggregation; 5th submit —
// four consecutive broker GPUAcquisitionTimeouts, never measured.)
//   R16 ceiling: agg FETCH = 8 XCD x 30 MB compulsory h-fill (238 MB) at
//   ~3.6 TB/s random-line rate -> 77us for each K=512 layer.
//   R17: split agg into
//     stats_kernel  - per-node wave: softmax m/l (LDS e-cache) + materialize
//                     per-edge weight w[e][h] fp16 (4 MB), zero next as/ad.
//     gather_slice  - column-sliced SpMM: slice = blockIdx%NSLICE -> XCD
//                     affinity; each XCD only touches a 64-col (128 B/row,
//                     line-aligned) slice of h = 3.84 MB -> L2-resident.
//                     w/src streamed with nontemporal loads, out written
//                     nontemporal so streams don't evict the h slice.
//   GEMM unchanged: fp16 MFMA, BKK=64, 32 KB LDS, XCD swizzle, fused alpha
//   epilogue. Conv prologue fused in one dispatch. CSR build unchanged.
// ---------------------------------------------------------------------------

typedef __attribute__((ext_vector_type(8))) _Float16 f16x8;
typedef __attribute__((ext_vector_type(4))) float floatx4;
typedef __attribute__((ext_vector_type(8))) unsigned short usv8;
typedef __attribute__((ext_vector_type(4))) unsigned short usv4;

#define DEG_CAP 256

__device__ __forceinline__ float lrelu(float e) {
    return (e > 0.f) ? e : 0.2f * e;
}
__device__ __forceinline__ void gload16(const void* g, void* l) {
    __builtin_amdgcn_global_load_lds(
        (const __attribute__((address_space(1))) void*)g,
        (__attribute__((address_space(3))) void*)l, 16, 0, 0);
}
__device__ __forceinline__ float ushort2floath(unsigned short u) {
    union { unsigned short u; __half h; } cv;
    cv.u = u;
    return __half2float(cv.h);
}

// ---------------------------------------------------------------------------
// CSR build
// ---------------------------------------------------------------------------
static __global__ void zero_int(int* __restrict__ p, int n) {
    int i = blockIdx.x * blockDim.x + threadIdx.x;
    if (i < n) p[i] = 0;
}

static __global__ void hist_kernel(const int* __restrict__ ei, int e0, int n_nodes,
                                   int* __restrict__ counts) {
    int e = blockIdx.x * blockDim.x + threadIdx.x;
    int et = e0 + n_nodes;
    if (e >= et) return;
    int d = (e < e0) ? ei[e0 + e] : (e - e0);
    atomicAdd(&counts[d], 1);
}

static __global__ void scan_kernel(const int* __restrict__ counts,
                                   int* __restrict__ row_ptr,
                                   int* __restrict__ cursor, int n) {
    __shared__ int sdata[1024];
    int tid = threadIdx.x;
    int per = (n + 1023) / 1024;
    int start = tid * per;
    int stop = min(start + per, n);
    if (start > n) start = n;
    int s = 0;
    for (int i = start; i < stop; i++) s += counts[i];
    sdata[tid] = s;
    __syncthreads();
    for (int off = 1; off < 1024; off <<= 1) {
        int t = (tid >= off) ? sdata[tid - off] : 0;
        __syncthreads();
        sdata[tid] += t;
        __syncthreads();
    }
    int run = sdata[tid] - s;
    for (int i = start; i < stop; i++) {
        row_ptr[i] = run;
        cursor[i] = run;
        run += counts[i];
    }
    if (stop == n) row_ptr[n] = run;
}

static __global__ void scatter_kernel(const int* __restrict__ ei, int e0, int n_nodes,
                                      int* __restrict__ cursor,
                                      int* __restrict__ src_sorted) {
    int e = blockIdx.x * blockDim.x + threadIdx.x;
    int et = e0 + n_nodes;
    if (e >= et) return;
    int s, d;
    if (e < e0) { s = ei[e]; d = ei[e0 + e]; } else { s = e - e0; d = s; }
    int pos = atomicAdd(&cursor[d], 1);
    src_sorted[pos] = s;
}

// ---------------------------------------------------------------------------
// fused conversion prologue: x -> fp16 A, 4x W -> fp16 W^T, zero as/ad.
// ---------------------------------------------------------------------------
__device__ __forceinline__ void convW_one(const float* W, __half* BT,
                                          int idx, int K, int N) {
    int n = idx / K, k = idx % K;
    float v = (n < N) ? W[(size_t)k * N + n] : 0.f;
    BT[(size_t)n * K + k] = __float2half(v);
}

static __global__ void conv_all(const float* __restrict__ X, __half* __restrict__ A, int nx,
                                const float* __restrict__ W1, __half* __restrict__ BT1,
                                const float* __restrict__ W2, __half* __restrict__ BT2,
                                const float* __restrict__ W3, __half* __restrict__ BT3,
                                const float* __restrict__ W4, __half* __restrict__ BT4,
                                float* __restrict__ zero_as, int nzero) {
    int idx = blockIdx.x * 256 + threadIdx.x;
    if (idx < nx) { A[idx] = __float2half(X[idx]); return; }
    idx -= nx;
    if (idx < 131072) { convW_one(W1, BT1, idx, 256, 512); return; }
    idx -= 131072;
    if (idx < 262144) { convW_one(W2, BT2, idx, 512, 512); return; }
    idx -= 262144;
    if (idx < 131072) { convW_one(W3, BT3, idx, 512, 256); return; }
    idx -= 131072;
    if (idx < 32768)  { convW_one(W4, BT4, idx, 256, 64); return; }
    idx -= 32768;
    if (idx < nzero) zero_as[idx] = 0.f;
}

// ---------------------------------------------------------------------------
// fp16 MFMA GEMM: C = A_f16 x B_f16. BKK=64, 32 KB LDS (A|B), 32 MFMAs per
// barrier, XCD-aware 1-D swizzle, fused alpha epilogue, fp16 C.
// Bank swizzle: 8 chunks/row, XOR with row&7.
// ---------------------------------------------------------------------------
#define BM 128
#define BN 128
#define BKK 64

__launch_bounds__(256, 4)
static __global__ void gemm_mfma(const __half* __restrict__ A,
                                 const __half* __restrict__ B,
                                 __half* __restrict__ C, int M, int K, int N,
                                 int xcols, int mblocks,
                                 const float* __restrict__ asv,
                                 const float* __restrict__ adv,
                                 float* __restrict__ as_out,
                                 float* __restrict__ ad_out,
                                 int Hh, int Cc) {
    __shared__ __align__(16) __half lds[2 * BM * BKK];   // 32 KB
    const int tid  = threadIdx.x;
    const int lane = tid & 63;
    const int wave = tid >> 6;

    const int id = blockIdx.x;
    const int band = id / (8 * xcols);
    const int rem = id - band * 8 * xcols;
    const int band_rows = min(8, mblocks - band * 8);
    const int ry = rem % band_rows;
    const int rx = rem / band_rows;
    const int r0 = (band * 8 + ry) * BM;
    const int c0 = rx * BN;

    const int wm = (wave >> 1) * 64;
    const int wn = (wave & 1) * 64;
    const int q   = lane >> 4;        // 0..3
    const int m16 = lane & 15;

    floatx4 acc[4][4];
#pragma unroll
    for (int i = 0; i < 4; i++)
#pragma unroll
        for (int j = 0; j < 4; j++) acc[i][j] = {0.f, 0.f, 0.f, 0.f};

    char* ldsb = (char*)lds;

#pragma unroll 1
    for (int k0 = 0; k0 < K; k0 += BKK) {
        __syncthreads();
#pragma unroll
        for (int c = 0; c < 4; c++) {
            int slot = c * 256 + tid;      // 0..1023
            int row = slot >> 3;           // 0..127
            int gc  = (slot & 7) ^ (row & 7);
            gload16(A + (size_t)(r0 + row) * K + k0 + gc * 8,
                    ldsb + slot * 16);                       // A
            gload16(B + (size_t)(c0 + row) * K + k0 + gc * 8,
                    ldsb + 16384 + slot * 16);               // B
        }
        __syncthreads();
#pragma unroll
        for (int ks = 0; ks < 2; ks++) {
            f16x8 af[4], bf[4];
#pragma unroll
            for (int i = 0; i < 4; i++) {
                int row = wm + i * 16 + m16;
                int ch  = (q + ks * 4) ^ (row & 7);
                af[i] = *(const f16x8*)(ldsb + (row * 8 + ch) * 16);
            }
#pragma unroll
            for (int j = 0; j < 4; j++) {
                int row = wn + j * 16 + m16;
                int ch  = (q + ks * 4) ^ (row & 7);
                bf[j] = *(const f16x8*)(ldsb + 16384 + (row * 8 + ch) * 16);
            }
#pragma unroll
            for (int i = 0; i < 4; i++)
#pragma unroll
                for (int j = 0; j < 4; j++)
                    acc[i][j] = __builtin_amdgcn_mfma_f32_16x16x32_f16(
                        af[i], bf[j], acc[i][j], 0, 0, 0);
        }
    }
    // C store (fp16). C/D layout: col = lane&15, row = (lane>>4)*4 + reg
#pragma unroll
    for (int i = 0; i < 4; i++)
#pragma unroll
        for (int j = 0; j < 4; j++)
#pragma unroll
            for (int r = 0; r < 4; r++) {
                int row = r0 + wm + i * 16 + q * 4 + r;
                int col = c0 + wn + j * 16 + m16;
                if (row < M && col < N)
                    C[(size_t)row * N + col] = __float2half(acc[i][j][r]);
            }
    // fused alpha epilogue: wave's 64-col chunk is head-uniform (C in {64,128}).
    if (c0 + wn < N) {
        int head = (c0 + wn) / Cc;
#pragma unroll
        for (int i = 0; i < 4; i++)
#pragma unroll
            for (int r = 0; r < 4; r++) {
                float ps = 0.f, pd = 0.f;
#pragma unroll
                for (int j = 0; j < 4; j++) {
                    int c = c0 + wn + j * 16 + m16;
                    float v = acc[i][j][r];
                    ps = fmaf(v, asv[c], ps);
                    pd = fmaf(v, adv[c], pd);
                }
#pragma unroll
                for (int off = 1; off < 16; off <<= 1) {
                    ps += __shfl_xor(ps, off);
                    pd += __shfl_xor(pd, off);
                }
                if (m16 == 0) {
                    int row = r0 + wm + i * 16 + q * 4 + r;
                    if (row < M) {
                        atomicAdd(&as_out[(size_t)row * Hh + head], ps);
                        atomicAdd(&ad_out[(size_t)row * Hh + head], pd);
                    }
                }
            }
    }
}

// ---------------------------------------------------------------------------
// stats kernel: one wave/node. Pass 1: per-head online softmax (m, l) with
// LDS e-cache (as before). Pass 2: materialize final per-edge weight
// w[e][h] = exp(e - m_h) / l_h as fp16 (nontemporal store, streaming).
// Epilogue zeroes next layer's as/ad ping-pong.
// ---------------------------------------------------------------------------
template <int H>
__launch_bounds__(256)
static __global__ void stats_kernel(const float* __restrict__ as_arr,
                                    const float* __restrict__ ad_arr,
                                    const int* __restrict__ row_ptr,
                                    const int* __restrict__ src_sorted,
                                    __half* __restrict__ w_arr,
                                    float* __restrict__ znext_as,
                                    float* __restrict__ znext_ad, int n_nodes) {
    __shared__ float lds_e[4][DEG_CAP * H];
    int wave = threadIdx.x >> 6;
    int lane = threadIdx.x & 63;
    int n = blockIdx.x * 4 + wave;
    if (n >= n_nodes) return;
    int beg = row_ptr[n], end = row_ptr[n + 1];
    float* we = lds_e[wave];

    // ---- pass 1: per-head m, l; cache e in LDS ----
    float ad_h[H], m_h[H], l_h[H];
#pragma unroll
    for (int hh = 0; hh < H; hh++) {
        ad_h[hh] = ad_arr[(size_t)n * H + hh];
        m_h[hh] = -INFINITY;
        l_h[hh] = 0.f;
    }
    for (int base = beg; base < end; base += 64) {
        int j = base + lane;
        bool ok = j < end;
        float e_h[H];
        if (ok) {
            int s = src_sorted[j];
            if constexpr (H == 4) {
                float4 a = ((const float4*)as_arr)[s];
                e_h[0] = lrelu(a.x + ad_h[0]);
                e_h[1] = lrelu(a.y + ad_h[1]);
                e_h[2] = lrelu(a.z + ad_h[2]);
                e_h[3] = lrelu(a.w + ad_h[3]);
            } else {
                e_h[0] = lrelu(as_arr[s] + ad_h[0]);
            }
            int idx = j - beg;
            if (idx < DEG_CAP) {
                if constexpr (H == 4) {
                    *(float4*)&we[idx * 4] = make_float4(e_h[0], e_h[1], e_h[2], e_h[3]);
                } else {
                    we[idx] = e_h[0];
                }
            }
        } else {
#pragma unroll
            for (int hh = 0; hh < H; hh++) e_h[hh] = -INFINITY;
        }
#pragma unroll
        for (int hh = 0; hh < H; hh++) {
            float cm = e_h[hh];
#pragma unroll
            for (int off = 1; off < 64; off <<= 1) cm = fmaxf(cm, __shfl_xor(cm, off));
            float newm = fmaxf(m_h[hh], cm);
            float p = ok ? __expf(e_h[hh] - newm) : 0.f;
#pragma unroll
            for (int off = 1; off < 64; off <<= 1) p += __shfl_xor(p, off);
            l_h[hh] = l_h[hh] * __expf(m_h[hh] - newm) + p;
            m_h[hh] = newm;
        }
    }
    float inv_h[H];
#pragma unroll
    for (int hh = 0; hh < H; hh++) inv_h[hh] = 1.f / l_h[hh];

    // ---- pass 2: write per-edge fp16 weights (streaming) ----
    for (int base = beg; base < end; base += 64) {
        int j = base + lane;
        if (j < end) {
            int idx = j - beg;
            float e_h[H];
            if (idx < DEG_CAP) {
                if constexpr (H == 4) {
                    float4 t = *(float4*)&we[idx * 4];
                    e_h[0] = t.x; e_h[1] = t.y; e_h[2] = t.z; e_h[3] = t.w;
                } else {
                    e_h[0] = we[idx];
                }
            } else {
                int s = src_sorted[j];
                if constexpr (H == 4) {
                    float4 a = ((const float4*)as_arr)[s];
                    e_h[0] = lrelu(a.x + ad_h[0]);
                    e_h[1] = lrelu(a.y + ad_h[1]);
                    e_h[2] = lrelu(a.z + ad_h[2]);
                    e_h[3] = lrelu(a.w + ad_h[3]);
                } else {
                    e_h[0] = lrelu(as_arr[s] + ad_h[0]);
                }
            }
            if constexpr (H == 4) {
                usv4 v;
#pragma unroll
                for (int hh = 0; hh < 4; hh++)
                    v[hh] = __half_as_ushort(
                        __float2half(__expf(e_h[hh] - m_h[hh]) * inv_h[hh]));
                __builtin_nontemporal_store(
                    v, (usv4*)((unsigned short*)w_arr + (size_t)j * 4));
            } else {
                unsigned short u = __half_as_ushort(
                    __float2half(__expf(e_h[0] - m_h[0]) * inv_h[0]));
                __builtin_nontemporal_store(u, (unsigned short*)w_arr + j);
            }
        }
    }

    if (znext_as != nullptr && lane == 0) {
        if constexpr (H == 4) {
            *(float4*)&znext_as[(size_t)n * 4] = make_float4(0.f, 0.f, 0.f, 0.f);
            *(float4*)&znext_ad[(size_t)n * 4] = make_float4(0.f, 0.f, 0.f, 0.f);
        } else {
            znext_as[n] = 0.f;
            znext_ad[n] = 0.f;
        }
    }
}

// ---------------------------------------------------------------------------
// column-sliced gather: slice = blockIdx % NSLICE -> XCD affinity (round-
// robin dispatch). Each XCD touches only a 64-col slice of h (128 B/row,
// cache-line aligned) = K/8 KB * 30000 rows <= 3.84 MB -> L2-resident.
// w / src_sorted are streamed nontemporal; out stored nontemporal.
// One wave handles NPW consecutive nodes for its 64-col slice (1 col/lane).
// ---------------------------------------------------------------------------
template <int H, int C, bool F16OUT>
__launch_bounds__(256)
static __global__ void gather_slice(const __half* __restrict__ h,
                                    const __half* __restrict__ w_arr,
                                    const int* __restrict__ row_ptr,
                                    const int* __restrict__ src_sorted,
                                    const float* __restrict__ bias,
                                    float* __restrict__ outf,
                                    __half* __restrict__ outh, int n_nodes) {
    constexpr int K = H * C;
    constexpr int NSLICE = K / 64;
    constexpr int NPW = 8;
    const int wave = threadIdx.x >> 6;
    const int lane = threadIdx.x & 63;
    const int slice = blockIdx.x % NSLICE;
    const int group = blockIdx.x / NSLICE;
    const int col = slice * 64 + lane;
    const int head = col / C;          // wave-uniform (64 | C)
    const float bcol = bias[col];
    const unsigned short* wp = (const unsigned short*)w_arr;

    int n0 = (group * 4 + wave) * NPW;
    for (int ni = 0; ni < NPW; ni++) {
        int n = n0 + ni;
        if (n >= n_nodes) return;
        int beg = row_ptr[n], end = row_ptr[n + 1];
        float acc = 0.f;
        int j = beg;
        for (; j + 3 < end; j += 4) {
            int s0 = __builtin_nontemporal_load(src_sorted + j);
            int s1 = __builtin_nontemporal_load(src_sorted + j + 1);
            int s2 = __builtin_nontemporal_load(src_sorted + j + 2);
            int s3 = __builtin_nontemporal_load(src_sorted + j + 3);
            float w0 = ushort2floath(
                __builtin_nontemporal_load(wp + (size_t)(j + 0) * H + head));
            float w1 = ushort2floath(
                __builtin_nontemporal_load(wp + (size_t)(j + 1) * H + head));
            float w2 = ushort2floath(
                __builtin_nontemporal_load(wp + (size_t)(j + 2) * H + head));
            float w3 = ushort2floath(
                __builtin_nontemporal_load(wp + (size_t)(j + 3) * H + head));
            acc = fmaf(w0, __half2float(h[(size_t)s0 * K + col]), acc);
            acc = fmaf(w1, __half2float(h[(size_t)s1 * K + col]), acc);
            acc = fmaf(w2, __half2float(h[(size_t)s2 * K + col]), acc);
            acc = fmaf(w3, __half2float(h[(size_t)s3 * K + col]), acc);
        }
        for (; j < end; j++) {
            int s0 = __builtin_nontemporal_load(src_sorted + j);
            float w0 = ushort2floath(
                __builtin_nontemporal_load(wp + (size_t)j * H + head));
            acc = fmaf(w0, __half2float(h[(size_t)s0 * K + col]), acc);
        }
        float v = fmaxf(acc + bcol, 0.f);
        if constexpr (F16OUT) {
            __builtin_nontemporal_store(
                __half_as_ushort(__float2half(v)),
                (unsigned short*)outh + (size_t)n * K + col);
        } else {
            __builtin_nontemporal_store(v, outf + (size_t)n * K + col);
        }
    }
}

// ---------------------------------------------------------------------------

static inline size_t align_up(size_t x) { return (x + 255) & ~(size_t)255; }

extern "C" void kernel_launch(void* const* d_in, const int* in_sizes, int n_in,
                              void* d_out, int out_size, void* d_ws, size_t ws_size,
                              hipStream_t stream) {
    const float* x   = (const float*)d_in[0];
    const int*   ei  = (const int*)d_in[1];
    const float* W1  = (const float*)d_in[2];
    const float* a1s = (const float*)d_in[3];
    const float* a1d = (const float*)d_in[4];
    const float* b1  = (const float*)d_in[5];
    const float* W2  = (const float*)d_in[6];
    const float* a2s = (const float*)d_in[7];
    const float* a2d = (const float*)d_in[8];
    const float* b2  = (const float*)d_in[9];
    const float* W3  = (const float*)d_in[10];
    const float* a3s = (const float*)d_in[11];
    const float* a3d = (const float*)d_in[12];
    const float* b3  = (const float*)d_in[13];
    const float* W4  = (const float*)d_in[14];
    const float* a4s = (const float*)d_in[15];
    const float* a4d = (const float*)d_in[16];
    const float* b4  = (const float*)d_in[17];

    const int n  = in_sizes[0] / 256;    // 30000
    const int e0 = in_sizes[1] / 2;      // 480000
    const int et = e0 + n;
    const int Mpad = ((n + 127) / 128) * 128;   // 30080

    // workspace layout (~104 MB)
    char* w = (char*)d_ws;
    __half* bufA = (__half*)w;                   w += align_up((size_t)Mpad * 512 * 2);
    __half* bufB = (__half*)w;                   w += align_up((size_t)Mpad * 512 * 2);
    __half* hbuf = (__half*)w;                   w += align_up((size_t)Mpad * 512 * 2);
    __half* WT1 = (__half*)w;                    w += align_up((size_t)512 * 256 * 2);
    __half* WT2 = (__half*)w;                    w += align_up((size_t)512 * 512 * 2);
    __half* WT3 = (__half*)w;                    w += align_up((size_t)256 * 512 * 2);
    __half* WT4 = (__half*)w;                    w += align_up((size_t)128 * 256 * 2);
    float* asA = (float*)w;                      w += align_up((size_t)n * 4 * 4);
    float* adA = (float*)w;                      w += align_up((size_t)n * 4 * 4);
    float* asB = (float*)w;                      w += align_up((size_t)n * 4 * 4);
    float* adB = (float*)w;                      w += align_up((size_t)n * 4 * 4);
    int* row_ptr = (int*)w;                      w += align_up((size_t)(n + 1) * 4);
    int* counts  = (int*)w;                      w += align_up((size_t)n * 4);
    int* cursor  = (int*)w;                      w += align_up((size_t)n * 4);
    int* src_sorted = (int*)w;                   w += align_up((size_t)et * 4);
    __half* wbuf = (__half*)w;                   w += align_up((size_t)et * 4 * 2);
    (void)ws_size;

    dim3 blk(256);
    int nodeblocks = (n + 3) / 4;
    int ggrp = (n + 31) / 32;   // gather groups: 4 waves x 8 nodes per block

    // ---- CSR build ----
    zero_int<<<(n + 255) / 256, 256, 0, stream>>>(counts, n);
    hist_kernel<<<(et + 255) / 256, 256, 0, stream>>>(ei, e0, n, counts);
    scan_kernel<<<1, 1024, 0, stream>>>(counts, row_ptr, cursor, n);
    scatter_kernel<<<(et + 255) / 256, 256, 0, stream>>>(ei, e0, n, cursor, src_sorted);

    // ---- fused conversion prologue (x + 4 weights + as/ad zero) ----
    const int nx = n * 256;
    conv_all<<<(nx + 557056 + n * 8 + 255) / 256, blk, 0, stream>>>(
        x, bufA, nx, W1, WT1, W2, WT2, W3, WT3, W4, WT4, asA, n * 8);

    const int mblocks = Mpad / 128;   // 235

    // ---- Layer 1: K=256 -> N=512 (4 heads x 128) ----
    gemm_mfma<<<dim3(4 * mblocks), blk, 0, stream>>>(bufA, WT1, hbuf, n, 256, 512, 4, mblocks,
                                                     a1s, a1d, asA, adA, 4, 128);
    stats_kernel<4><<<nodeblocks, blk, 0, stream>>>(asA, adA, row_ptr, src_sorted, wbuf, asB, adB, n);
    gather_slice<4, 128, true><<<dim3(8 * ggrp), blk, 0, stream>>>(
        hbuf, wbuf, row_ptr, src_sorted, b1, nullptr, bufB, n);

    // ---- Layer 2: K=512 -> N=512 ----
    gemm_mfma<<<dim3(4 * mblocks), blk, 0, stream>>>(bufB, WT2, hbuf, n, 512, 512, 4, mblocks,
                                                     a2s, a2d, asB, adB, 4, 128);
    stats_kernel<4><<<nodeblocks, blk, 0, stream>>>(asB, adB, row_ptr, src_sorted, wbuf, asA, adA, n);
    gather_slice<4, 128, true><<<dim3(8 * ggrp), blk, 0, stream>>>(
        hbuf, wbuf, row_ptr, src_sorted, b2, nullptr, bufA, n);

    // ---- Layer 3: K=512 -> N=256 (4 heads x 64) ----
    gemm_mfma<<<dim3(2 * mblocks), blk, 0, stream>>>(bufA, WT3, hbuf, n, 512, 256, 2, mblocks,
                                                     a3s, a3d, asA, adA, 4, 64);
    stats_kernel<4><<<nodeblocks, blk, 0, stream>>>(asA, adA, row_ptr, src_sorted, wbuf, asB, adB, n);
    gather_slice<4, 64, true><<<dim3(4 * ggrp), blk, 0, stream>>>(
        hbuf, wbuf, row_ptr, src_sorted, b3, nullptr, bufB, n);

    // ---- Layer 4: K=256 -> N=64, 1 head ----
    gemm_mfma<<<dim3(1 * mblocks), blk, 0, stream>>>(bufB, WT4, hbuf, n, 256, 64, 1, mblocks,
                                                     a4s, a4d, asB, adB, 1, 64);
    stats_kernel<1><<<nodeblocks, blk, 0, stream>>>(asB, adB, row_ptr, src_sorted, wbuf, nullptr, nullptr, n);
    gather_slice<1, 64, false><<<dim3(1 * ggrp), blk, 0, stream>>>(
        hbuf, wbuf, row_ptr, src_sorted, b4, (float*)d_out, nullptr, n);
}

// Round 8
// 742.765 us; speedup vs baseline: 1.3320x; 1.3320x over previous
//
#include <hip/hip_runtime.h>
#include <hip/hip_fp16.h>
#include <math.h>

// ---------------------------------------------------------------------------
// GAT 4-layer forward.  (R18 = R17 with wide-load sliced gather; resubmit —
// broker timeouts, never measured.)
//   R17 measured: FETCH 238->90 MB (XCD slicing WORKS) but gather 77->213us:
//   2B/lane h-loads made it latency/issue-bound (hbm 7%, VALU 29%, nothing
//   saturated). R18 keeps the 64-col XCD slice but re-decomposes the wave:
//   lane = (edge-sub es 0..7) x (col-group cg 0..7); each lane loads 16B of
//   h (8 halves) for edge j+es -> one dwordx4 covers 8 edges x 64 cols =
//   8x fewer memory instructions/edge. w stored head-major [H][Epad] so a
//   group's w is one 2B load; src one 4B load; tail masked by w=0.
//   Per-node shfl_xor(8,16,32) reduces edge-sub partials; es==0 lanes store.
//   stats_kernel: unchanged except head-major w stores.
//   GEMM / conv prologue / CSR build unchanged.
// ---------------------------------------------------------------------------

typedef __attribute__((ext_vector_type(8))) _Float16 f16x8;
typedef __attribute__((ext_vector_type(4))) float floatx4;
typedef __attribute__((ext_vector_type(8))) unsigned short usv8;
typedef __attribute__((ext_vector_type(4))) unsigned short usv4;

#define DEG_CAP 256

__device__ __forceinline__ float lrelu(float e) {
    return (e > 0.f) ? e : 0.2f * e;
}
__device__ __forceinline__ void gload16(const void* g, void* l) {
    __builtin_amdgcn_global_load_lds(
        (const __attribute__((address_space(1))) void*)g,
        (__attribute__((address_space(3))) void*)l, 16, 0, 0);
}
__device__ __forceinline__ float ushort2floath(unsigned short u) {
    union { unsigned short u; __half h; } cv;
    cv.u = u;
    return __half2float(cv.h);
}

// ---------------------------------------------------------------------------
// CSR build
// ---------------------------------------------------------------------------
static __global__ void zero_int(int* __restrict__ p, int n) {
    int i = blockIdx.x * blockDim.x + threadIdx.x;
    if (i < n) p[i] = 0;
}

static __global__ void hist_kernel(const int* __restrict__ ei, int e0, int n_nodes,
                                   int* __restrict__ counts) {
    int e = blockIdx.x * blockDim.x + threadIdx.x;
    int et = e0 + n_nodes;
    if (e >= et) return;
    int d = (e < e0) ? ei[e0 + e] : (e - e0);
    atomicAdd(&counts[d], 1);
}

static __global__ void scan_kernel(const int* __restrict__ counts,
                                   int* __restrict__ row_ptr,
                                   int* __restrict__ cursor, int n) {
    __shared__ int sdata[1024];
    int tid = threadIdx.x;
    int per = (n + 1023) / 1024;
    int start = tid * per;
    int stop = min(start + per, n);
    if (start > n) start = n;
    int s = 0;
    for (int i = start; i < stop; i++) s += counts[i];
    sdata[tid] = s;
    __syncthreads();
    for (int off = 1; off < 1024; off <<= 1) {
        int t = (tid >= off) ? sdata[tid - off] : 0;
        __syncthreads();
        sdata[tid] += t;
        __syncthreads();
    }
    int run = sdata[tid] - s;
    for (int i = start; i < stop; i++) {
        row_ptr[i] = run;
        cursor[i] = run;
        run += counts[i];
    }
    if (stop == n) row_ptr[n] = run;
}

static __global__ void scatter_kernel(const int* __restrict__ ei, int e0, int n_nodes,
                                      int* __restrict__ cursor,
                                      int* __restrict__ src_sorted) {
    int e = blockIdx.x * blockDim.x + threadIdx.x;
    int et = e0 + n_nodes;
    if (e >= et) return;
    int s, d;
    if (e < e0) { s = ei[e]; d = ei[e0 + e]; } else { s = e - e0; d = s; }
    int pos = atomicAdd(&cursor[d], 1);
    src_sorted[pos] = s;
}

// ---------------------------------------------------------------------------
// fused conversion prologue: x -> fp16 A, 4x W -> fp16 W^T, zero as/ad.
// ---------------------------------------------------------------------------
__device__ __forceinline__ void convW_one(const float* W, __half* BT,
                                          int idx, int K, int N) {
    int n = idx / K, k = idx % K;
    float v = (n < N) ? W[(size_t)k * N + n] : 0.f;
    BT[(size_t)n * K + k] = __float2half(v);
}

static __global__ void conv_all(const float* __restrict__ X, __half* __restrict__ A, int nx,
                                const float* __restrict__ W1, __half* __restrict__ BT1,
                                const float* __restrict__ W2, __half* __restrict__ BT2,
                                const float* __restrict__ W3, __half* __restrict__ BT3,
                                const float* __restrict__ W4, __half* __restrict__ BT4,
                                float* __restrict__ zero_as, int nzero) {
    int idx = blockIdx.x * 256 + threadIdx.x;
    if (idx < nx) { A[idx] = __float2half(X[idx]); return; }
    idx -= nx;
    if (idx < 131072) { convW_one(W1, BT1, idx, 256, 512); return; }
    idx -= 131072;
    if (idx < 262144) { convW_one(W2, BT2, idx, 512, 512); return; }
    idx -= 262144;
    if (idx < 131072) { convW_one(W3, BT3, idx, 512, 256); return; }
    idx -= 131072;
    if (idx < 32768)  { convW_one(W4, BT4, idx, 256, 64); return; }
    idx -= 32768;
    if (idx < nzero) zero_as[idx] = 0.f;
}

// ---------------------------------------------------------------------------
// fp16 MFMA GEMM: C = A_f16 x B_f16. BKK=64, 32 KB LDS (A|B), 32 MFMAs per
// barrier, XCD-aware 1-D swizzle, fused alpha epilogue, fp16 C.
// Bank swizzle: 8 chunks/row, XOR with row&7.
// ---------------------------------------------------------------------------
#define BM 128
#define BN 128
#define BKK 64

__launch_bounds__(256, 4)
static __global__ void gemm_mfma(const __half* __restrict__ A,
                                 const __half* __restrict__ B,
                                 __half* __restrict__ C, int M, int K, int N,
                                 int xcols, int mblocks,
                                 const float* __restrict__ asv,
                                 const float* __restrict__ adv,
                                 float* __restrict__ as_out,
                                 float* __restrict__ ad_out,
                                 int Hh, int Cc) {
    __shared__ __align__(16) __half lds[2 * BM * BKK];   // 32 KB
    const int tid  = threadIdx.x;
    const int lane = tid & 63;
    const int wave = tid >> 6;

    const int id = blockIdx.x;
    const int band = id / (8 * xcols);
    const int rem = id - band * 8 * xcols;
    const int band_rows = min(8, mblocks - band * 8);
    const int ry = rem % band_rows;
    const int rx = rem / band_rows;
    const int r0 = (band * 8 + ry) * BM;
    const int c0 = rx * BN;

    const int wm = (wave >> 1) * 64;
    const int wn = (wave & 1) * 64;
    const int q   = lane >> 4;        // 0..3
    const int m16 = lane & 15;

    floatx4 acc[4][4];
#pragma unroll
    for (int i = 0; i < 4; i++)
#pragma unroll
        for (int j = 0; j < 4; j++) acc[i][j] = {0.f, 0.f, 0.f, 0.f};

    char* ldsb = (char*)lds;

#pragma unroll 1
    for (int k0 = 0; k0 < K; k0 += BKK) {
        __syncthreads();
#pragma unroll
        for (int c = 0; c < 4; c++) {
            int slot = c * 256 + tid;      // 0..1023
            int row = slot >> 3;           // 0..127
            int gc  = (slot & 7) ^ (row & 7);
            gload16(A + (size_t)(r0 + row) * K + k0 + gc * 8,
                    ldsb + slot * 16);                       // A
            gload16(B + (size_t)(c0 + row) * K + k0 + gc * 8,
                    ldsb + 16384 + slot * 16);               // B
        }
        __syncthreads();
#pragma unroll
        for (int ks = 0; ks < 2; ks++) {
            f16x8 af[4], bf[4];
#pragma unroll
            for (int i = 0; i < 4; i++) {
                int row = wm + i * 16 + m16;
                int ch  = (q + ks * 4) ^ (row & 7);
                af[i] = *(const f16x8*)(ldsb + (row * 8 + ch) * 16);
            }
#pragma unroll
            for (int j = 0; j < 4; j++) {
                int row = wn + j * 16 + m16;
                int ch  = (q + ks * 4) ^ (row & 7);
                bf[j] = *(const f16x8*)(ldsb + 16384 + (row * 8 + ch) * 16);
            }
#pragma unroll
            for (int i = 0; i < 4; i++)
#pragma unroll
                for (int j = 0; j < 4; j++)
                    acc[i][j] = __builtin_amdgcn_mfma_f32_16x16x32_f16(
                        af[i], bf[j], acc[i][j], 0, 0, 0);
        }
    }
    // C store (fp16). C/D layout: col = lane&15, row = (lane>>4)*4 + reg
#pragma unroll
    for (int i = 0; i < 4; i++)
#pragma unroll
        for (int j = 0; j < 4; j++)
#pragma unroll
            for (int r = 0; r < 4; r++) {
                int row = r0 + wm + i * 16 + q * 4 + r;
                int col = c0 + wn + j * 16 + m16;
                if (row < M && col < N)
                    C[(size_t)row * N + col] = __float2half(acc[i][j][r]);
            }
    // fused alpha epilogue: wave's 64-col chunk is head-uniform (C in {64,128}).
    if (c0 + wn < N) {
        int head = (c0 + wn) / Cc;
#pragma unroll
        for (int i = 0; i < 4; i++)
#pragma unroll
            for (int r = 0; r < 4; r++) {
                float ps = 0.f, pd = 0.f;
#pragma unroll
                for (int j = 0; j < 4; j++) {
                    int c = c0 + wn + j * 16 + m16;
                    float v = acc[i][j][r];
                    ps = fmaf(v, asv[c], ps);
                    pd = fmaf(v, adv[c], pd);
                }
#pragma unroll
                for (int off = 1; off < 16; off <<= 1) {
                    ps += __shfl_xor(ps, off);
                    pd += __shfl_xor(pd, off);
                }
                if (m16 == 0) {
                    int row = r0 + wm + i * 16 + q * 4 + r;
                    if (row < M) {
                        atomicAdd(&as_out[(size_t)row * Hh + head], ps);
                        atomicAdd(&ad_out[(size_t)row * Hh + head], pd);
                    }
                }
            }
    }
}

// ---------------------------------------------------------------------------
// stats kernel: one wave/node. Pass 1: per-head online softmax (m, l) with
// LDS e-cache. Pass 2: materialize final per-edge weight exp(e-m)/l as fp16,
// HEAD-MAJOR layout w[h][Epad] (so gather groups read contiguous w).
// Epilogue zeroes next layer's as/ad ping-pong.
// ---------------------------------------------------------------------------
template <int H>
__launch_bounds__(256)
static __global__ void stats_kernel(const float* __restrict__ as_arr,
                                    const float* __restrict__ ad_arr,
                                    const int* __restrict__ row_ptr,
                                    const int* __restrict__ src_sorted,
                                    __half* __restrict__ w_arr, int Epad,
                                    float* __restrict__ znext_as,
                                    float* __restrict__ znext_ad, int n_nodes) {
    __shared__ float lds_e[4][DEG_CAP * H];
    int wave = threadIdx.x >> 6;
    int lane = threadIdx.x & 63;
    int n = blockIdx.x * 4 + wave;
    if (n >= n_nodes) return;
    int beg = row_ptr[n], end = row_ptr[n + 1];
    float* we = lds_e[wave];

    // ---- pass 1: per-head m, l; cache e in LDS ----
    float ad_h[H], m_h[H], l_h[H];
#pragma unroll
    for (int hh = 0; hh < H; hh++) {
        ad_h[hh] = ad_arr[(size_t)n * H + hh];
        m_h[hh] = -INFINITY;
        l_h[hh] = 0.f;
    }
    for (int base = beg; base < end; base += 64) {
        int j = base + lane;
        bool ok = j < end;
        float e_h[H];
        if (ok) {
            int s = src_sorted[j];
            if constexpr (H == 4) {
                float4 a = ((const float4*)as_arr)[s];
                e_h[0] = lrelu(a.x + ad_h[0]);
                e_h[1] = lrelu(a.y + ad_h[1]);
                e_h[2] = lrelu(a.z + ad_h[2]);
                e_h[3] = lrelu(a.w + ad_h[3]);
            } else {
                e_h[0] = lrelu(as_arr[s] + ad_h[0]);
            }
            int idx = j - beg;
            if (idx < DEG_CAP) {
                if constexpr (H == 4) {
                    *(float4*)&we[idx * 4] = make_float4(e_h[0], e_h[1], e_h[2], e_h[3]);
                } else {
                    we[idx] = e_h[0];
                }
            }
        } else {
#pragma unroll
            for (int hh = 0; hh < H; hh++) e_h[hh] = -INFINITY;
        }
#pragma unroll
        for (int hh = 0; hh < H; hh++) {
            float cm = e_h[hh];
#pragma unroll
            for (int off = 1; off < 64; off <<= 1) cm = fmaxf(cm, __shfl_xor(cm, off));
            float newm = fmaxf(m_h[hh], cm);
            float p = ok ? __expf(e_h[hh] - newm) : 0.f;
#pragma unroll
            for (int off = 1; off < 64; off <<= 1) p += __shfl_xor(p, off);
            l_h[hh] = l_h[hh] * __expf(m_h[hh] - newm) + p;
            m_h[hh] = newm;
        }
    }
    float inv_h[H];
#pragma unroll
    for (int hh = 0; hh < H; hh++) inv_h[hh] = 1.f / l_h[hh];

    // ---- pass 2: write per-edge fp16 weights, head-major (streaming) ----
    unsigned short* wp = (unsigned short*)w_arr;
    for (int base = beg; base < end; base += 64) {
        int j = base + lane;
        if (j < end) {
            int idx = j - beg;
            float e_h[H];
            if (idx < DEG_CAP) {
                if constexpr (H == 4) {
                    float4 t = *(float4*)&we[idx * 4];
                    e_h[0] = t.x; e_h[1] = t.y; e_h[2] = t.z; e_h[3] = t.w;
                } else {
                    e_h[0] = we[idx];
                }
            } else {
                int s = src_sorted[j];
                if constexpr (H == 4) {
                    float4 a = ((const float4*)as_arr)[s];
                    e_h[0] = lrelu(a.x + ad_h[0]);
                    e_h[1] = lrelu(a.y + ad_h[1]);
                    e_h[2] = lrelu(a.z + ad_h[2]);
                    e_h[3] = lrelu(a.w + ad_h[3]);
                } else {
                    e_h[0] = lrelu(as_arr[s] + ad_h[0]);
                }
            }
#pragma unroll
            for (int hh = 0; hh < H; hh++)
                __builtin_nontemporal_store(
                    __half_as_ushort(__float2half(
                        __expf(e_h[hh] - m_h[hh]) * inv_h[hh])),
                    wp + (size_t)hh * Epad + j);
        }
    }

    if (znext_as != nullptr && lane == 0) {
        if constexpr (H == 4) {
            *(float4*)&znext_as[(size_t)n * 4] = make_float4(0.f, 0.f, 0.f, 0.f);
            *(float4*)&znext_ad[(size_t)n * 4] = make_float4(0.f, 0.f, 0.f, 0.f);
        } else {
            znext_as[n] = 0.f;
            znext_ad[n] = 0.f;
        }
    }
}

// ---------------------------------------------------------------------------
// wide-load sliced gather: slice = blockIdx % NSLICE -> XCD affinity (keeps
// R17's measured FETCH win: each XCD touches one 64-col slice = 3.84 MB,
// L2-resident). Wave is 2-D: lane = es*8+cg, es = edge-sub (8 edges/iter),
// cg = col-group (8 cols, 16B). One dwordx4/lane covers 8 edges x 64 cols
// -> 8x fewer mem insts than R17's 2B/lane version (its measured failure).
// head is wave-uniform (64 | C). Tail edges masked via w=0.
// Per-node shfl_xor(8/16/32) reduce; es==0 lanes store the slice output.
// ---------------------------------------------------------------------------
template <int H, int C, bool F16OUT>
__launch_bounds__(256)
static __global__ void gather_slice(const __half* __restrict__ h,
                                    const __half* __restrict__ w_arr,
                                    const int* __restrict__ row_ptr,
                                    const int* __restrict__ src_sorted,
                                    const float* __restrict__ bias,
                                    float* __restrict__ outf,
                                    __half* __restrict__ outh,
                                    int n_nodes, int Epad) {
    constexpr int K = H * C;
    constexpr int NSLICE = K / 64;
    constexpr int NPW = 8;
    const int wave = threadIdx.x >> 6;
    const int lane = threadIdx.x & 63;
    const int es = lane >> 3;        // edge-sub 0..7
    const int cg = lane & 7;         // col-group 0..7 (8 cols each)
    const int slice = blockIdx.x % NSLICE;
    const int group = blockIdx.x / NSLICE;
    const int colbase = slice * 64 + cg * 8;
    const int head = (slice * 64) / C;   // wave-uniform (64 | C)
    const unsigned short* wp = (const unsigned short*)w_arr + (size_t)head * Epad;

    // hoisted per-lane bias (8 cols)
    float bloc[8];
    {
        float4 b0 = *(const float4*)(bias + colbase);
        float4 b1 = *(const float4*)(bias + colbase + 4);
        bloc[0] = b0.x; bloc[1] = b0.y; bloc[2] = b0.z; bloc[3] = b0.w;
        bloc[4] = b1.x; bloc[5] = b1.y; bloc[6] = b1.z; bloc[7] = b1.w;
    }

    int n0 = (group * 4 + wave) * NPW;
    for (int ni = 0; ni < NPW; ni++) {
        int n = n0 + ni;
        if (n >= n_nodes) return;
        int beg = row_ptr[n], end = row_ptr[n + 1];
        float acc[8];
#pragma unroll
        for (int r = 0; r < 8; r++) acc[r] = 0.f;

        for (int j = beg; j < end; j += 8) {
            int rem = end - j;
            int e = (es < rem) ? es : 0;                  // clamp tail
            int s = __builtin_nontemporal_load(src_sorted + j + e);
            float wv = ushort2floath(
                __builtin_nontemporal_load(wp + j + e));
            if (es >= rem) wv = 0.f;                      // mask tail
            float4 raw = *(const float4*)(h + (size_t)s * K + colbase);
            const __half* hv = (const __half*)&raw;
#pragma unroll
            for (int r = 0; r < 8; r++)
                acc[r] = fmaf(wv, __half2float(hv[r]), acc[r]);
        }

        // reduce over edge-sub groups (lanes at stride 8)
#pragma unroll
        for (int off = 8; off < 64; off <<= 1)
#pragma unroll
            for (int r = 0; r < 8; r++)
                acc[r] += __shfl_xor(acc[r], off);

        if (es == 0) {
            float v[8];
#pragma unroll
            for (int r = 0; r < 8; r++) v[r] = fmaxf(acc[r] + bloc[r], 0.f);
            if constexpr (F16OUT) {
                usv8 o;
#pragma unroll
                for (int r = 0; r < 8; r++)
                    o[r] = __half_as_ushort(__float2half(v[r]));
                __builtin_nontemporal_store(
                    o, (usv8*)((unsigned short*)outh + (size_t)n * K + colbase));
            } else {
                floatx4 o0 = {v[0], v[1], v[2], v[3]};
                floatx4 o1 = {v[4], v[5], v[6], v[7]};
                __builtin_nontemporal_store(
                    o0, (floatx4*)(outf + (size_t)n * K + colbase));
                __builtin_nontemporal_store(
                    o1, (floatx4*)(outf + (size_t)n * K + colbase + 4));
            }
        }
    }
}

// ---------------------------------------------------------------------------

static inline size_t align_up(size_t x) { return (x + 255) & ~(size_t)255; }

extern "C" void kernel_launch(void* const* d_in, const int* in_sizes, int n_in,
                              void* d_out, int out_size, void* d_ws, size_t ws_size,
                              hipStream_t stream) {
    const float* x   = (const float*)d_in[0];
    const int*   ei  = (const int*)d_in[1];
    const float* W1  = (const float*)d_in[2];
    const float* a1s = (const float*)d_in[3];
    const float* a1d = (const float*)d_in[4];
    const float* b1  = (const float*)d_in[5];
    const float* W2  = (const float*)d_in[6];
    const float* a2s = (const float*)d_in[7];
    const float* a2d = (const float*)d_in[8];
    const float* b2  = (const float*)d_in[9];
    const float* W3  = (const float*)d_in[10];
    const float* a3s = (const float*)d_in[11];
    const float* a3d = (const float*)d_in[12];
    const float* b3  = (const float*)d_in[13];
    const float* W4  = (const float*)d_in[14];
    const float* a4s = (const float*)d_in[15];
    const float* a4d = (const float*)d_in[16];
    const float* b4  = (const float*)d_in[17];

    const int n  = in_sizes[0] / 256;    // 30000
    const int e0 = in_sizes[1] / 2;      // 480000
    const int et = e0 + n;
    const int Mpad = ((n + 127) / 128) * 128;   // 30080
    const int Epad = ((et + 255) / 256) * 256;  // head-major w plane stride

    // workspace layout (~104 MB)
    char* w = (char*)d_ws;
    __half* bufA = (__half*)w;                   w += align_up((size_t)Mpad * 512 * 2);
    __half* bufB = (__half*)w;                   w += align_up((size_t)Mpad * 512 * 2);
    __half* hbuf = (__half*)w;                   w += align_up((size_t)Mpad * 512 * 2);
    __half* WT1 = (__half*)w;                    w += align_up((size_t)512 * 256 * 2);
    __half* WT2 = (__half*)w;                    w += align_up((size_t)512 * 512 * 2);
    __half* WT3 = (__half*)w;                    w += align_up((size_t)256 * 512 * 2);
    __half* WT4 = (__half*)w;                    w += align_up((size_t)128 * 256 * 2);
    float* asA = (float*)w;                      w += align_up((size_t)n * 4 * 4);
    float* adA = (float*)w;                      w += align_up((size_t)n * 4 * 4);
    float* asB = (float*)w;                      w += align_up((size_t)n * 4 * 4);
    float* adB = (float*)w;                      w += align_up((size_t)n * 4 * 4);
    int* row_ptr = (int*)w;                      w += align_up((size_t)(n + 1) * 4);
    int* counts  = (int*)w;                      w += align_up((size_t)n * 4);
    int* cursor  = (int*)w;                      w += align_up((size_t)n * 4);
    int* src_sorted = (int*)w;                   w += align_up((size_t)et * 4);
    __half* wbuf = (__half*)w;                   w += align_up((size_t)Epad * 4 * 2);
    (void)ws_size;

    dim3 blk(256);
    int nodeblocks = (n + 3) / 4;
    int ggrp = (n + 31) / 32;   // gather groups: 4 waves x 8 nodes per block

    // ---- CSR build ----
    zero_int<<<(n + 255) / 256, 256, 0, stream>>>(counts, n);
    hist_kernel<<<(et + 255) / 256, 256, 0, stream>>>(ei, e0, n, counts);
    scan_kernel<<<1, 1024, 0, stream>>>(counts, row_ptr, cursor, n);
    scatter_kernel<<<(et + 255) / 256, 256, 0, stream>>>(ei, e0, n, cursor, src_sorted);

    // ---- fused conversion prologue (x + 4 weights + as/ad zero) ----
    const int nx = n * 256;
    conv_all<<<(nx + 557056 + n * 8 + 255) / 256, blk, 0, stream>>>(
        x, bufA, nx, W1, WT1, W2, WT2, W3, WT3, W4, WT4, asA, n * 8);

    const int mblocks = Mpad / 128;   // 235

    // ---- Layer 1: K=256 -> N=512 (4 heads x 128) ----
    gemm_mfma<<<dim3(4 * mblocks), blk, 0, stream>>>(bufA, WT1, hbuf, n, 256, 512, 4, mblocks,
                                                     a1s, a1d, asA, adA, 4, 128);
    stats_kernel<4><<<nodeblocks, blk, 0, stream>>>(asA, adA, row_ptr, src_sorted, wbuf, Epad, asB, adB, n);
    gather_slice<4, 128, true><<<dim3(8 * ggrp), blk, 0, stream>>>(
        hbuf, wbuf, row_ptr, src_sorted, b1, nullptr, bufB, n, Epad);

    // ---- Layer 2: K=512 -> N=512 ----
    gemm_mfma<<<dim3(4 * mblocks), blk, 0, stream>>>(bufB, WT2, hbuf, n, 512, 512, 4, mblocks,
                                                     a2s, a2d, asB, adB, 4, 128);
    stats_kernel<4><<<nodeblocks, blk, 0, stream>>>(asB, adB, row_ptr, src_sorted, wbuf, Epad, asA, adA, n);
    gather_slice<4, 128, true><<<dim3(8 * ggrp), blk, 0, stream>>>(
        hbuf, wbuf, row_ptr, src_sorted, b2, nullptr, bufA, n, Epad);

    // ---- Layer 3: K=512 -> N=256 (4 heads x 64) ----
    gemm_mfma<<<dim3(2 * mblocks), blk, 0, stream>>>(bufA, WT3, hbuf, n, 512, 256, 2, mblocks,
                                                     a3s, a3d, asA, adA, 4, 64);
    stats_kernel<4><<<nodeblocks, blk, 0, stream>>>(asA, adA, row_ptr, src_sorted, wbuf, Epad, asB, adB, n);
    gather_slice<4, 64, true><<<dim3(4 * ggrp), blk, 0, stream>>>(
        hbuf, wbuf, row_ptr, src_sorted, b3, nullptr, bufB, n, Epad);

    // ---- Layer 4: K=256 -> N=64, 1 head ----
    gemm_mfma<<<dim3(1 * mblocks), blk, 0, stream>>>(bufB, WT4, hbuf, n, 256, 64, 1, mblocks,
                                                     a4s, a4d, asB, adB, 1, 64);
    stats_kernel<1><<<nodeblocks, blk, 0, stream>>>(asB, adB, row_ptr, src_sorted, wbuf, Epad, nullptr, nullptr, n);
    gather_slice<1, 64, false><<<dim3(1 * ggrp), blk, 0, stream>>>(
        hbuf, wbuf, row_ptr, src_sorted, b4, (float*)d_out, nullptr, n, Epad);
}

// Round 9
// 680.926 us; speedup vs baseline: 1.4529x; 1.0908x over previous
//
#include <hip/hip_runtime.h>
#include <hip/hip_fp16.h>
#include <math.h>

// ---------------------------------------------------------------------------
// GAT 4-layer forward.  (R19 = R18 with group-per-node gather, no reduction)
//   R17 measured: XCD slicing works (FETCH 238->90 MB) but 2B loads -> 213us.
//   R18 measured: wide dwordx4 loads -> 121us, FETCH 58MB, HBM 9%, VALU 53%:
//   still issue/latency-bound. Culprit: 24x ds_bpermute + 24 add reduction
//   per node-slice (240K/layer, 3-deep DS dependent chain) + per-iter tail
//   masking -- epilogue cost ~ gather cost at avg degree 17.
//   R19: lane = (node-group g 0..7) x (col-lane cg 0..7). Each 8-lane group
//   owns ONE node; lanes own disjoint 8-col chunks of the 64-col slice.
//   Same per-edge loads (broadcast src/w + dwordx4 h), but acc is lane-
//   private -> NO cross-lane reduction, no tail masks; epilogue = bias+relu+
//   16B store per lane. 2x edge unroll for ILP. Slice->XCD affinity kept.
//   stats_kernel (head-major w) / GEMM / conv prologue / CSR unchanged.
// ---------------------------------------------------------------------------

typedef __attribute__((ext_vector_type(8))) _Float16 f16x8;
typedef __attribute__((ext_vector_type(4))) float floatx4;
typedef __attribute__((ext_vector_type(8))) unsigned short usv8;
typedef __attribute__((ext_vector_type(4))) unsigned short usv4;

#define DEG_CAP 256

__device__ __forceinline__ float lrelu(float e) {
    return (e > 0.f) ? e : 0.2f * e;
}
__device__ __forceinline__ void gload16(const void* g, void* l) {
    __builtin_amdgcn_global_load_lds(
        (const __attribute__((address_space(1))) void*)g,
        (__attribute__((address_space(3))) void*)l, 16, 0, 0);
}
__device__ __forceinline__ float ushort2floath(unsigned short u) {
    union { unsigned short u; __half h; } cv;
    cv.u = u;
    return __half2float(cv.h);
}

// ---------------------------------------------------------------------------
// CSR build
// ---------------------------------------------------------------------------
static __global__ void zero_int(int* __restrict__ p, int n) {
    int i = blockIdx.x * blockDim.x + threadIdx.x;
    if (i < n) p[i] = 0;
}

static __global__ void hist_kernel(const int* __restrict__ ei, int e0, int n_nodes,
                                   int* __restrict__ counts) {
    int e = blockIdx.x * blockDim.x + threadIdx.x;
    int et = e0 + n_nodes;
    if (e >= et) return;
    int d = (e < e0) ? ei[e0 + e] : (e - e0);
    atomicAdd(&counts[d], 1);
}

static __global__ void scan_kernel(const int* __restrict__ counts,
                                   int* __restrict__ row_ptr,
                                   int* __restrict__ cursor, int n) {
    __shared__ int sdata[1024];
    int tid = threadIdx.x;
    int per = (n + 1023) / 1024;
    int start = tid * per;
    int stop = min(start + per, n);
    if (start > n) start = n;
    int s = 0;
    for (int i = start; i < stop; i++) s += counts[i];
    sdata[tid] = s;
    __syncthreads();
    for (int off = 1; off < 1024; off <<= 1) {
        int t = (tid >= off) ? sdata[tid - off] : 0;
        __syncthreads();
        sdata[tid] += t;
        __syncthreads();
    }
    int run = sdata[tid] - s;
    for (int i = start; i < stop; i++) {
        row_ptr[i] = run;
        cursor[i] = run;
        run += counts[i];
    }
    if (stop == n) row_ptr[n] = run;
}

static __global__ void scatter_kernel(const int* __restrict__ ei, int e0, int n_nodes,
                                      int* __restrict__ cursor,
                                      int* __restrict__ src_sorted) {
    int e = blockIdx.x * blockDim.x + threadIdx.x;
    int et = e0 + n_nodes;
    if (e >= et) return;
    int s, d;
    if (e < e0) { s = ei[e]; d = ei[e0 + e]; } else { s = e - e0; d = s; }
    int pos = atomicAdd(&cursor[d], 1);
    src_sorted[pos] = s;
}

// ---------------------------------------------------------------------------
// fused conversion prologue: x -> fp16 A, 4x W -> fp16 W^T, zero as/ad.
// ---------------------------------------------------------------------------
__device__ __forceinline__ void convW_one(const float* W, __half* BT,
                                          int idx, int K, int N) {
    int n = idx / K, k = idx % K;
    float v = (n < N) ? W[(size_t)k * N + n] : 0.f;
    BT[(size_t)n * K + k] = __float2half(v);
}

static __global__ void conv_all(const float* __restrict__ X, __half* __restrict__ A, int nx,
                                const float* __restrict__ W1, __half* __restrict__ BT1,
                                const float* __restrict__ W2, __half* __restrict__ BT2,
                                const float* __restrict__ W3, __half* __restrict__ BT3,
                                const float* __restrict__ W4, __half* __restrict__ BT4,
                                float* __restrict__ zero_as, int nzero) {
    int idx = blockIdx.x * 256 + threadIdx.x;
    if (idx < nx) { A[idx] = __float2half(X[idx]); return; }
    idx -= nx;
    if (idx < 131072) { convW_one(W1, BT1, idx, 256, 512); return; }
    idx -= 131072;
    if (idx < 262144) { convW_one(W2, BT2, idx, 512, 512); return; }
    idx -= 262144;
    if (idx < 131072) { convW_one(W3, BT3, idx, 512, 256); return; }
    idx -= 131072;
    if (idx < 32768)  { convW_one(W4, BT4, idx, 256, 64); return; }
    idx -= 32768;
    if (idx < nzero) zero_as[idx] = 0.f;
}

// ---------------------------------------------------------------------------
// fp16 MFMA GEMM: C = A_f16 x B_f16. BKK=64, 32 KB LDS (A|B), 32 MFMAs per
// barrier, XCD-aware 1-D swizzle, fused alpha epilogue, fp16 C.
// Bank swizzle: 8 chunks/row, XOR with row&7.
// ---------------------------------------------------------------------------
#define BM 128
#define BN 128
#define BKK 64

__launch_bounds__(256, 4)
static __global__ void gemm_mfma(const __half* __restrict__ A,
                                 const __half* __restrict__ B,
                                 __half* __restrict__ C, int M, int K, int N,
                                 int xcols, int mblocks,
                                 const float* __restrict__ asv,
                                 const float* __restrict__ adv,
                                 float* __restrict__ as_out,
                                 float* __restrict__ ad_out,
                                 int Hh, int Cc) {
    __shared__ __align__(16) __half lds[2 * BM * BKK];   // 32 KB
    const int tid  = threadIdx.x;
    const int lane = tid & 63;
    const int wave = tid >> 6;

    const int id = blockIdx.x;
    const int band = id / (8 * xcols);
    const int rem = id - band * 8 * xcols;
    const int band_rows = min(8, mblocks - band * 8);
    const int ry = rem % band_rows;
    const int rx = rem / band_rows;
    const int r0 = (band * 8 + ry) * BM;
    const int c0 = rx * BN;

    const int wm = (wave >> 1) * 64;
    const int wn = (wave & 1) * 64;
    const int q   = lane >> 4;        // 0..3
    const int m16 = lane & 15;

    floatx4 acc[4][4];
#pragma unroll
    for (int i = 0; i < 4; i++)
#pragma unroll
        for (int j = 0; j < 4; j++) acc[i][j] = {0.f, 0.f, 0.f, 0.f};

    char* ldsb = (char*)lds;

#pragma unroll 1
    for (int k0 = 0; k0 < K; k0 += BKK) {
        __syncthreads();
#pragma unroll
        for (int c = 0; c < 4; c++) {
            int slot = c * 256 + tid;      // 0..1023
            int row = slot >> 3;           // 0..127
            int gc  = (slot & 7) ^ (row & 7);
            gload16(A + (size_t)(r0 + row) * K + k0 + gc * 8,
                    ldsb + slot * 16);                       // A
            gload16(B + (size_t)(c0 + row) * K + k0 + gc * 8,
                    ldsb + 16384 + slot * 16);               // B
        }
        __syncthreads();
#pragma unroll
        for (int ks = 0; ks < 2; ks++) {
            f16x8 af[4], bf[4];
#pragma unroll
            for (int i = 0; i < 4; i++) {
                int row = wm + i * 16 + m16;
                int ch  = (q + ks * 4) ^ (row & 7);
                af[i] = *(const f16x8*)(ldsb + (row * 8 + ch) * 16);
            }
#pragma unroll
            for (int j = 0; j < 4; j++) {
                int row = wn + j * 16 + m16;
                int ch  = (q + ks * 4) ^ (row & 7);
                bf[j] = *(const f16x8*)(ldsb + 16384 + (row * 8 + ch) * 16);
            }
#pragma unroll
            for (int i = 0; i < 4; i++)
#pragma unroll
                for (int j = 0; j < 4; j++)
                    acc[i][j] = __builtin_amdgcn_mfma_f32_16x16x32_f16(
                        af[i], bf[j], acc[i][j], 0, 0, 0);
        }
    }
    // C store (fp16). C/D layout: col = lane&15, row = (lane>>4)*4 + reg
#pragma unroll
    for (int i = 0; i < 4; i++)
#pragma unroll
        for (int j = 0; j < 4; j++)
#pragma unroll
            for (int r = 0; r < 4; r++) {
                int row = r0 + wm + i * 16 + q * 4 + r;
                int col = c0 + wn + j * 16 + m16;
                if (row < M && col < N)
                    C[(size_t)row * N + col] = __float2half(acc[i][j][r]);
            }
    // fused alpha epilogue: wave's 64-col chunk is head-uniform (C in {64,128}).
    if (c0 + wn < N) {
        int head = (c0 + wn) / Cc;
#pragma unroll
        for (int i = 0; i < 4; i++)
#pragma unroll
            for (int r = 0; r < 4; r++) {
                float ps = 0.f, pd = 0.f;
#pragma unroll
                for (int j = 0; j < 4; j++) {
                    int c = c0 + wn + j * 16 + m16;
                    float v = acc[i][j][r];
                    ps = fmaf(v, asv[c], ps);
                    pd = fmaf(v, adv[c], pd);
                }
#pragma unroll
                for (int off = 1; off < 16; off <<= 1) {
                    ps += __shfl_xor(ps, off);
                    pd += __shfl_xor(pd, off);
                }
                if (m16 == 0) {
                    int row = r0 + wm + i * 16 + q * 4 + r;
                    if (row < M) {
                        atomicAdd(&as_out[(size_t)row * Hh + head], ps);
                        atomicAdd(&ad_out[(size_t)row * Hh + head], pd);
                    }
                }
            }
    }
}

// ---------------------------------------------------------------------------
// stats kernel: one wave/node. Pass 1: per-head online softmax (m, l) with
// LDS e-cache. Pass 2: materialize final per-edge weight exp(e-m)/l as fp16,
// HEAD-MAJOR layout w[h][Epad] (so gather groups read contiguous w).
// Epilogue zeroes next layer's as/ad ping-pong.
// ---------------------------------------------------------------------------
template <int H>
__launch_bounds__(256)
static __global__ void stats_kernel(const float* __restrict__ as_arr,
                                    const float* __restrict__ ad_arr,
                                    const int* __restrict__ row_ptr,
                                    const int* __restrict__ src_sorted,
                                    __half* __restrict__ w_arr, int Epad,
                                    float* __restrict__ znext_as,
                                    float* __restrict__ znext_ad, int n_nodes) {
    __shared__ float lds_e[4][DEG_CAP * H];
    int wave = threadIdx.x >> 6;
    int lane = threadIdx.x & 63;
    int n = blockIdx.x * 4 + wave;
    if (n >= n_nodes) return;
    int beg = row_ptr[n], end = row_ptr[n + 1];
    float* we = lds_e[wave];

    // ---- pass 1: per-head m, l; cache e in LDS ----
    float ad_h[H], m_h[H], l_h[H];
#pragma unroll
    for (int hh = 0; hh < H; hh++) {
        ad_h[hh] = ad_arr[(size_t)n * H + hh];
        m_h[hh] = -INFINITY;
        l_h[hh] = 0.f;
    }
    for (int base = beg; base < end; base += 64) {
        int j = base + lane;
        bool ok = j < end;
        float e_h[H];
        if (ok) {
            int s = src_sorted[j];
            if constexpr (H == 4) {
                float4 a = ((const float4*)as_arr)[s];
                e_h[0] = lrelu(a.x + ad_h[0]);
                e_h[1] = lrelu(a.y + ad_h[1]);
                e_h[2] = lrelu(a.z + ad_h[2]);
                e_h[3] = lrelu(a.w + ad_h[3]);
            } else {
                e_h[0] = lrelu(as_arr[s] + ad_h[0]);
            }
            int idx = j - beg;
            if (idx < DEG_CAP) {
                if constexpr (H == 4) {
                    *(float4*)&we[idx * 4] = make_float4(e_h[0], e_h[1], e_h[2], e_h[3]);
                } else {
                    we[idx] = e_h[0];
                }
            }
        } else {
#pragma unroll
            for (int hh = 0; hh < H; hh++) e_h[hh] = -INFINITY;
        }
#pragma unroll
        for (int hh = 0; hh < H; hh++) {
            float cm = e_h[hh];
#pragma unroll
            for (int off = 1; off < 64; off <<= 1) cm = fmaxf(cm, __shfl_xor(cm, off));
            float newm = fmaxf(m_h[hh], cm);
            float p = ok ? __expf(e_h[hh] - newm) : 0.f;
#pragma unroll
            for (int off = 1; off < 64; off <<= 1) p += __shfl_xor(p, off);
            l_h[hh] = l_h[hh] * __expf(m_h[hh] - newm) + p;
            m_h[hh] = newm;
        }
    }
    float inv_h[H];
#pragma unroll
    for (int hh = 0; hh < H; hh++) inv_h[hh] = 1.f / l_h[hh];

    // ---- pass 2: write per-edge fp16 weights, head-major (streaming) ----
    unsigned short* wp = (unsigned short*)w_arr;
    for (int base = beg; base < end; base += 64) {
        int j = base + lane;
        if (j < end) {
            int idx = j - beg;
            float e_h[H];
            if (idx < DEG_CAP) {
                if constexpr (H == 4) {
                    float4 t = *(float4*)&we[idx * 4];
                    e_h[0] = t.x; e_h[1] = t.y; e_h[2] = t.z; e_h[3] = t.w;
                } else {
                    e_h[0] = we[idx];
                }
            } else {
                int s = src_sorted[j];
                if constexpr (H == 4) {
                    float4 a = ((const float4*)as_arr)[s];
                    e_h[0] = lrelu(a.x + ad_h[0]);
                    e_h[1] = lrelu(a.y + ad_h[1]);
                    e_h[2] = lrelu(a.z + ad_h[2]);
                    e_h[3] = lrelu(a.w + ad_h[3]);
                } else {
                    e_h[0] = lrelu(as_arr[s] + ad_h[0]);
                }
            }
#pragma unroll
            for (int hh = 0; hh < H; hh++)
                __builtin_nontemporal_store(
                    __half_as_ushort(__float2half(
                        __expf(e_h[hh] - m_h[hh]) * inv_h[hh])),
                    wp + (size_t)hh * Epad + j);
        }
    }

    if (znext_as != nullptr && lane == 0) {
        if constexpr (H == 4) {
            *(float4*)&znext_as[(size_t)n * 4] = make_float4(0.f, 0.f, 0.f, 0.f);
            *(float4*)&znext_ad[(size_t)n * 4] = make_float4(0.f, 0.f, 0.f, 0.f);
        } else {
            znext_as[n] = 0.f;
            znext_ad[n] = 0.f;
        }
    }
}

// ---------------------------------------------------------------------------
// group-per-node sliced gather: slice = blockIdx % NSLICE -> XCD affinity
// (keeps the measured FETCH win: 64-col slice = 3.84 MB, L2-resident).
// lane = g*8+cg: group g (8 lanes) owns node n0+g; lane cg owns cols
// colbase = slice*64 + cg*8 (16B). Per edge: broadcast src/w loads + one
// dwordx4 h load per lane; acc is lane-private for disjoint cols -> NO
// cross-lane reduction (R18's 24x ds_bpermute epilogue eliminated), no
// tail masks. 2x edge unroll for ILP. All lanes store 16B at the end.
// src/w nontemporal (streams); h regular (must stay L2-resident).
// ---------------------------------------------------------------------------
template <int H, int C, bool F16OUT>
__launch_bounds__(256)
static __global__ void gather_slice(const __half* __restrict__ h,
                                    const __half* __restrict__ w_arr,
                                    const int* __restrict__ row_ptr,
                                    const int* __restrict__ src_sorted,
                                    const float* __restrict__ bias,
                                    float* __restrict__ outf,
                                    __half* __restrict__ outh,
                                    int n_nodes, int Epad) {
    constexpr int K = H * C;
    constexpr int NSLICE = K / 64;
    const int wave = threadIdx.x >> 6;
    const int lane = threadIdx.x & 63;
    const int g  = lane >> 3;        // node-group 0..7
    const int cg = lane & 7;         // col-lane 0..7 (8 cols, 16B)
    const int slice = blockIdx.x % NSLICE;
    const int group = blockIdx.x / NSLICE;
    const int colbase = slice * 64 + cg * 8;
    const int head = (slice * 64) / C;   // wave-uniform (64 | C)
    const unsigned short* wp = (const unsigned short*)w_arr + (size_t)head * Epad;

    // per-lane bias (8 cols) -- safe to load unconditionally (colbase+8 <= K)
    float bloc[8];
    {
        float4 b0 = *(const float4*)(bias + colbase);
        float4 b1 = *(const float4*)(bias + colbase + 4);
        bloc[0] = b0.x; bloc[1] = b0.y; bloc[2] = b0.z; bloc[3] = b0.w;
        bloc[4] = b1.x; bloc[5] = b1.y; bloc[6] = b1.z; bloc[7] = b1.w;
    }

    const int n = (group * 4 + wave) * 8 + g;     // 8 nodes per wave
    const bool valid = n < n_nodes;
    int beg = 0, end = 0;
    if (valid) { beg = row_ptr[n]; end = row_ptr[n + 1]; }

    float acc[8];
#pragma unroll
    for (int r = 0; r < 8; r++) acc[r] = 0.f;

    int j = beg;
    for (; j + 1 < end; j += 2) {     // 2 independent edges in flight
        int s0 = __builtin_nontemporal_load(src_sorted + j);
        int s1 = __builtin_nontemporal_load(src_sorted + j + 1);
        float w0 = ushort2floath(__builtin_nontemporal_load(wp + j));
        float w1 = ushort2floath(__builtin_nontemporal_load(wp + j + 1));
        float4 r0 = *(const float4*)(h + (size_t)s0 * K + colbase);
        float4 r1 = *(const float4*)(h + (size_t)s1 * K + colbase);
        const __half* h0 = (const __half*)&r0;
        const __half* h1 = (const __half*)&r1;
#pragma unroll
        for (int r = 0; r < 8; r++)
            acc[r] = fmaf(w0, __half2float(h0[r]), acc[r]);
#pragma unroll
        for (int r = 0; r < 8; r++)
            acc[r] = fmaf(w1, __half2float(h1[r]), acc[r]);
    }
    if (j < end) {
        int s0 = __builtin_nontemporal_load(src_sorted + j);
        float w0 = ushort2floath(__builtin_nontemporal_load(wp + j));
        float4 r0 = *(const float4*)(h + (size_t)s0 * K + colbase);
        const __half* h0 = (const __half*)&r0;
#pragma unroll
        for (int r = 0; r < 8; r++)
            acc[r] = fmaf(w0, __half2float(h0[r]), acc[r]);
    }

    if (valid) {
        float v[8];
#pragma unroll
        for (int r = 0; r < 8; r++) v[r] = fmaxf(acc[r] + bloc[r], 0.f);
        if constexpr (F16OUT) {
            usv8 o;
#pragma unroll
            for (int r = 0; r < 8; r++)
                o[r] = __half_as_ushort(__float2half(v[r]));
            __builtin_nontemporal_store(
                o, (usv8*)((unsigned short*)outh + (size_t)n * K + colbase));
        } else {
            floatx4 o0 = {v[0], v[1], v[2], v[3]};
            floatx4 o1 = {v[4], v[5], v[6], v[7]};
            __builtin_nontemporal_store(
                o0, (floatx4*)(outf + (size_t)n * K + colbase));
            __builtin_nontemporal_store(
                o1, (floatx4*)(outf + (size_t)n * K + colbase + 4));
        }
    }
}

// ---------------------------------------------------------------------------

static inline size_t align_up(size_t x) { return (x + 255) & ~(size_t)255; }

extern "C" void kernel_launch(void* const* d_in, const int* in_sizes, int n_in,
                              void* d_out, int out_size, void* d_ws, size_t ws_size,
                              hipStream_t stream) {
    const float* x   = (const float*)d_in[0];
    const int*   ei  = (const int*)d_in[1];
    const float* W1  = (const float*)d_in[2];
    const float* a1s = (const float*)d_in[3];
    const float* a1d = (const float*)d_in[4];
    const float* b1  = (const float*)d_in[5];
    const float* W2  = (const float*)d_in[6];
    const float* a2s = (const float*)d_in[7];
    const float* a2d = (const float*)d_in[8];
    const float* b2  = (const float*)d_in[9];
    const float* W3  = (const float*)d_in[10];
    const float* a3s = (const float*)d_in[11];
    const float* a3d = (const float*)d_in[12];
    const float* b3  = (const float*)d_in[13];
    const float* W4  = (const float*)d_in[14];
    const float* a4s = (const float*)d_in[15];
    const float* a4d = (const float*)d_in[16];
    const float* b4  = (const float*)d_in[17];

    const int n  = in_sizes[0] / 256;    // 30000
    const int e0 = in_sizes[1] / 2;      // 480000
    const int et = e0 + n;
    const int Mpad = ((n + 127) / 128) * 128;   // 30080
    const int Epad = ((et + 255) / 256) * 256;  // head-major w plane stride

    // workspace layout (~104 MB)
    char* w = (char*)d_ws;
    __half* bufA = (__half*)w;                   w += align_up((size_t)Mpad * 512 * 2);
    __half* bufB = (__half*)w;                   w += align_up((size_t)Mpad * 512 * 2);
    __half* hbuf = (__half*)w;                   w += align_up((size_t)Mpad * 512 * 2);
    __half* WT1 = (__half*)w;                    w += align_up((size_t)512 * 256 * 2);
    __half* WT2 = (__half*)w;                    w += align_up((size_t)512 * 512 * 2);
    __half* WT3 = (__half*)w;                    w += align_up((size_t)256 * 512 * 2);
    __half* WT4 = (__half*)w;                    w += align_up((size_t)128 * 256 * 2);
    float* asA = (float*)w;                      w += align_up((size_t)n * 4 * 4);
    float* adA = (float*)w;                      w += align_up((size_t)n * 4 * 4);
    float* asB = (float*)w;                      w += align_up((size_t)n * 4 * 4);
    float* adB = (float*)w;                      w += align_up((size_t)n * 4 * 4);
    int* row_ptr = (int*)w;                      w += align_up((size_t)(n + 1) * 4);
    int* counts  = (int*)w;                      w += align_up((size_t)n * 4);
    int* cursor  = (int*)w;                      w += align_up((size_t)n * 4);
    int* src_sorted = (int*)w;                   w += align_up((size_t)et * 4);
    __half* wbuf = (__half*)w;                   w += align_up((size_t)Epad * 4 * 2);
    (void)ws_size;

    dim3 blk(256);
    int nodeblocks = (n + 3) / 4;
    int ggrp = (n + 31) / 32;   // gather groups: 4 waves x 8 nodes per block

    // ---- CSR build ----
    zero_int<<<(n + 255) / 256, 256, 0, stream>>>(counts, n);
    hist_kernel<<<(et + 255) / 256, 256, 0, stream>>>(ei, e0, n, counts);
    scan_kernel<<<1, 1024, 0, stream>>>(counts, row_ptr, cursor, n);
    scatter_kernel<<<(et + 255) / 256, 256, 0, stream>>>(ei, e0, n, cursor, src_sorted);

    // ---- fused conversion prologue (x + 4 weights + as/ad zero) ----
    const int nx = n * 256;
    conv_all<<<(nx + 557056 + n * 8 + 255) / 256, blk, 0, stream>>>(
        x, bufA, nx, W1, WT1, W2, WT2, W3, WT3, W4, WT4, asA, n * 8);

    const int mblocks = Mpad / 128;   // 235

    // ---- Layer 1: K=256 -> N=512 (4 heads x 128) ----
    gemm_mfma<<<dim3(4 * mblocks), blk, 0, stream>>>(bufA, WT1, hbuf, n, 256, 512, 4, mblocks,
                                                     a1s, a1d, asA, adA, 4, 128);
    stats_kernel<4><<<nodeblocks, blk, 0, stream>>>(asA, adA, row_ptr, src_sorted, wbuf, Epad, asB, adB, n);
    gather_slice<4, 128, true><<<dim3(8 * ggrp), blk, 0, stream>>>(
        hbuf, wbuf, row_ptr, src_sorted, b1, nullptr, bufB, n, Epad);

    // ---- Layer 2: K=512 -> N=512 ----
    gemm_mfma<<<dim3(4 * mblocks), blk, 0, stream>>>(bufB, WT2, hbuf, n, 512, 512, 4, mblocks,
                                                     a2s, a2d, asB, adB, 4, 128);
    stats_kernel<4><<<nodeblocks, blk, 0, stream>>>(asB, adB, row_ptr, src_sorted, wbuf, Epad, asA, adA, n);
    gather_slice<4, 128, true><<<dim3(8 * ggrp), blk, 0, stream>>>(
        hbuf, wbuf, row_ptr, src_sorted, b2, nullptr, bufA, n, Epad);

    // ---- Layer 3: K=512 -> N=256 (4 heads x 64) ----
    gemm_mfma<<<dim3(2 * mblocks), blk, 0, stream>>>(bufA, WT3, hbuf, n, 512, 256, 2, mblocks,
                                                     a3s, a3d, asA, adA, 4, 64);
    stats_kernel<4><<<nodeblocks, blk, 0, stream>>>(asA, adA, row_ptr, src_sorted, wbuf, Epad, asB, adB, n);
    gather_slice<4, 64, true><<<dim3(4 * ggrp), blk, 0, stream>>>(
        hbuf, wbuf, row_ptr, src_sorted, b3, nullptr, bufB, n, Epad);

    // ---- Layer 4: K=256 -> N=64, 1 head ----
    gemm_mfma<<<dim3(1 * mblocks), blk, 0, stream>>>(bufB, WT4, hbuf, n, 256, 64, 1, mblocks,
                                                     a4s, a4d, asB, adB, 1, 64);
    stats_kernel<1><<<nodeblocks, blk, 0, stream>>>(asB, adB, row_ptr, src_sorted, wbuf, Epad, nullptr, nullptr, n);
    gather_slice<1, 64, false><<<dim3(1 * ggrp), blk, 0, stream>>>(
        hbuf, wbuf, row_ptr, src_sorted, b4, (float*)d_out, nullptr, n, Epad);
}